// Round 14
// baseline (1030.132 us; speedup 1.0000x reference)
//
#include <hip/hip_runtime.h>

// BeliefPropagation: N=50k, E=1.6M directed edges, q=8, 10 iters.
// R9 changes:
//  - bp_iter phase-2 scatter uses NON-TEMPORAL stores (bypass L2 allocate);
//    aux_kernel keeps regular stores as the in-profile control for the
//    1.25 TB/s random-sector-write ceiling theory.
//  - field_kernel fused into scanA (deg = count already loaded there).

constexpr int Q = 8;
constexpr int NITER = 10;
constexpr int TB = 256;
constexpr int TBW = 512;            // fused kernel block: 8 waves
constexpr int WPB = TBW / 64;       // waves (nodes) per block
constexpr int MAXDEG = 64;          // LDS capacity per node (deg>64 falls back)
constexpr int NSTRIPE = 64;         // NSTRIPE*Q == TBW required
constexpr int CSTRIDE = 16;         // count padding: 64B per counter
constexpr int SCB = 1024;           // counters per scan block

// ---- one-time: p_local[e] = rank of e among edges with same dst ----
__global__ void pass1_kernel(const int* __restrict__ dst, int* __restrict__ count,
                             int* __restrict__ p_local, int E) {
    int e = blockIdx.x * TB + threadIdx.x;
    if (e < E) p_local[e] = atomicAdd(&count[(size_t)dst[e] * CSTRIDE], 1);
}

// ---- one-time scanA: per-block exclusive scan of 1024 strided counters ----
// FUSED: field bootstrap hacc0 += deg[n] * psi_init[n,k]
__global__ void scanA_kernel(const int* __restrict__ count, int* __restrict__ row_start,
                             int* __restrict__ blocksum,
                             const float* __restrict__ psi,
                             float* __restrict__ hacc0, int N) {
    __shared__ int buf[SCB];
    __shared__ float wsum[SCB / 64][Q];
    int tid = threadIdx.x;
    int gi = blockIdx.x * SCB + tid;
    int v = (gi < N) ? count[(size_t)gi * CSTRIDE] : 0;
    buf[tid] = v;
    // fused field contribution (before first barrier)
    float c[Q];
    if (gi < N) {
        const float4* pp = reinterpret_cast<const float4*>(psi + (size_t)gi * Q);
        float4 a = pp[0], b = pp[1];
        float fv = (float)v;
        c[0] = fv * a.x; c[1] = fv * a.y; c[2] = fv * a.z; c[3] = fv * a.w;
        c[4] = fv * b.x; c[5] = fv * b.y; c[6] = fv * b.z; c[7] = fv * b.w;
    } else {
#pragma unroll
        for (int k = 0; k < Q; ++k) c[k] = 0.f;
    }
#pragma unroll
    for (int k = 0; k < Q; ++k) {
        float s = c[k];
        s += __shfl_xor(s, 1);  s += __shfl_xor(s, 2);
        s += __shfl_xor(s, 4);  s += __shfl_xor(s, 8);
        s += __shfl_xor(s, 16); s += __shfl_xor(s, 32);
        if ((tid & 63) == 0) wsum[tid >> 6][k] = s;
    }
    __syncthreads();
    for (int off = 1; off < SCB; off <<= 1) {
        int add = (tid >= off) ? buf[tid - off] : 0;
        __syncthreads();
        buf[tid] += add;
        __syncthreads();
    }
    if (gi < N) row_start[gi] = buf[tid] - v;            // local exclusive
    if (tid == SCB - 1) blocksum[blockIdx.x] = buf[tid]; // block total
    if (tid < Q) {
        float s = 0.f;
#pragma unroll
        for (int w = 0; w < SCB / 64; ++w) s += wsum[w][tid];
        atomicAdd(&hacc0[(blockIdx.x & (NSTRIPE - 1)) * Q + tid], s);
    }
}

// ---- one-time scanB: 1 wave scans block sums -> exclusive offsets; total -> row_start[N] ----
__global__ void scanB_kernel(int* __restrict__ blocksum, int* __restrict__ row_start,
                             int nblk, int N) {
    int tid = threadIdx.x;   // 64 threads, one wave
    int orig = (tid < nblk) ? blocksum[tid] : 0;
    int v = orig;
    for (int off = 1; off < 64; off <<= 1) {
        int u = __shfl_up(v, off);
        if (tid >= off) v += u;
    }
    if (tid < nblk) blocksum[tid] = v - orig;  // exclusive offset
    if (tid == nblk - 1) row_start[N] = v;     // grand total = E
}

// ---- one-time scanC: add block offsets ----
__global__ void scanC_kernel(int* __restrict__ row_start, const int* __restrict__ blocksum,
                             int N) {
    int gi = blockIdx.x * SCB + threadIdx.x;
    if (gi < N) row_start[gi] += blocksum[blockIdx.x];
}

// ---- one-time pair-form aux: thread per UNDIRECTED edge e (<M) ----
// handles e (s0->d0) and e+M (d0->s0); all reads contiguous.
// aux4[p] = {rev_pos, bits(ew_rev), orig_eid, 0}; mt0[p] = msg_init*ew
// NOTE: regular (cached) stores on purpose — control vs bp_iter's nt stores.
__global__ void aux_kernel(const int* __restrict__ src_row,
                           const int* __restrict__ dst_row,
                           const int* __restrict__ p_local,
                           const int* __restrict__ row_start,
                           const float* __restrict__ edge_attr,
                           const float* __restrict__ beta_p,
                           const float* __restrict__ msg_init,
                           int4* __restrict__ aux4,
                           float* __restrict__ mt0,
                           int M) {
    int e = blockIdx.x * TB + threadIdx.x;
    if (e >= M) return;
    int s0 = src_row[e], d0 = dst_row[e];
    float beta = *beta_p;
    float w  = expf(beta * edge_attr[e])     - 1.0f;   // ew of edge e
    float wr = expf(beta * edge_attr[e + M]) - 1.0f;   // ew of edge e+M
    int p  = row_start[d0] + p_local[e];       // CSR position of e   (dst=d0)
    int rp = row_start[s0] + p_local[e + M];   // CSR position of e+M (dst=s0)
    aux4[p]  = make_int4(rp, __float_as_int(wr), e, 0);
    aux4[rp] = make_int4(p,  __float_as_int(w),  e + M, 0);
    const float4* mp = reinterpret_cast<const float4*>(msg_init + (size_t)e * Q);
    float4 m0 = mp[0], m1 = mp[1];
    float4* op = reinterpret_cast<float4*>(mt0 + (size_t)p * Q);
    op[0] = make_float4(m0.x * w, m0.y * w, m0.z * w, m0.w * w);
    op[1] = make_float4(m1.x * w, m1.y * w, m1.z * w, m1.w * w);
    const float4* mq = reinterpret_cast<const float4*>(msg_init + (size_t)(e + M) * Q);
    float4 r0 = mq[0], r1 = mq[1];
    float4* oq = reinterpret_cast<float4*>(mt0 + (size_t)rp * Q);
    oq[0] = make_float4(r0.x * wr, r0.y * wr, r0.z * wr, r0.w * wr);
    oq[1] = make_float4(r1.x * wr, r1.y * wr, r1.z * wr, r1.w * wr);
}

// ---- per-iter fused kernel: wave-per-node; h derived in-block from hacc_cur ----
template <bool FINAL>
__global__ __launch_bounds__(TBW) void bp_iter_kernel(
    const float* __restrict__ mt_old,
    const int4*  __restrict__ aux4,
    const int*   __restrict__ row_start,
    const float* __restrict__ beta_p,
    const float* __restrict__ hacc_cur,   // read: field sums from prev iter
    float* __restrict__ hacc_nxt,         // accumulate: this iter's field sums
    float* __restrict__ hacc_zer,         // zeroed by block 0 for iter t+2
    float* __restrict__ out,              // FINAL: orig-order plain msg; else mt ping
    float* __restrict__ psi_out,
    int N, int M, float invN) {
    __shared__ float lbuf[WPB][MAXDEG * Q];   // 16 KB
    __shared__ int4  auxbuf[WPB][MAXDEG];     //  8 KB
    __shared__ float hpart[WPB][Q];
    __shared__ float accQ[Q];
    int tid = threadIdx.x;
    int wave = tid >> 6, lane = tid & 63, es = lane >> 3, k = lane & 7;

    // ---- prologue: h[k] = -(beta/N) * sum_s hacc_cur[s,k] (block-local) ----
    float v = hacc_cur[tid];                  // TBW == NSTRIPE*Q
    v += __shfl_xor(v, 8);
    v += __shfl_xor(v, 16);
    v += __shfl_xor(v, 32);
    if (lane < Q) hpart[wave][lane] = v;
    if (tid < Q) accQ[tid] = 0.f;
    if (blockIdx.x == 0) hacc_zer[tid] = 0.f;
    __syncthreads();
    float beta = *beta_p;
    float hk = 0.f;
#pragma unroll
    for (int w2 = 0; w2 < WPB; ++w2) hk += hpart[w2][k];
    hk *= -beta * invN;

    int n = blockIdx.x * WPB + wave;
    float contrib = 0.f;
    if (n < N) {
        int lo = row_start[n], hi = row_start[n + 1];
        // phase 1: stream mt, stage l + aux4 in LDS, reduce nlp
        float acc = 0.f;
        for (int i = lo + es; i < hi; i += 8) {
            int idx = i - lo;
            float mtv = mt_old[(size_t)i * Q + k];
            if (k == 0 && idx < MAXDEG) auxbuf[wave][idx] = aux4[i];
            float l = log1pf(mtv);
            if (idx < MAXDEG) lbuf[wave][idx * Q + k] = l;
            acc += l;
        }
        acc += __shfl_xor(acc, 8);
        acc += __shfl_xor(acc, 16);
        acc += __shfl_xor(acc, 32);
        float nlp = hk + acc;
        // psi + field contribution
        float pp = expf(nlp);
        float s = pp;
        s += __shfl_xor(s, 1);
        s += __shfl_xor(s, 2);
        s += __shfl_xor(s, 4);
        pp /= s;
        if (lane < Q) {
            if (FINAL) psi_out[(size_t)n * Q + k] = pp;
            contrib = (float)(hi - lo) * pp;
        }
        // phase 2: emit reply message per incoming edge (NT scatter stores)
        for (int i = lo + es; i < hi; i += 8) {
            int idx = i - lo;
            float l = (idx < MAXDEG) ? lbuf[wave][idx * Q + k]
                                     : log1pf(mt_old[(size_t)i * Q + k]);
            float t = expf(nlp - l);
            float ss = t;
            ss += __shfl_xor(ss, 1);
            ss += __shfl_xor(ss, 2);
            ss += __shfl_xor(ss, 4);
            float inv = 1.0f / ss;
            int4 a = (idx < MAXDEG) ? auxbuf[wave][idx] : aux4[i];
            if (FINAL) {
                int oe = (a.z < M) ? (a.z + M) : (a.z - M);  // orig id of reverse edge
                __builtin_nontemporal_store(t * inv, &out[(size_t)oe * Q + k]);
            } else {
                __builtin_nontemporal_store(t * inv * __int_as_float(a.y),
                                            &out[(size_t)a.x * Q + k]);
            }
        }
        if (lane < Q) atomicAdd(&accQ[k], contrib);
    }
    __syncthreads();
    if (tid < Q)
        atomicAdd(&hacc_nxt[(blockIdx.x & (NSTRIPE - 1)) * Q + tid], accQ[tid]);
}

extern "C" void kernel_launch(void* const* d_in, const int* in_sizes, int n_in,
                              void* d_out, int out_size, void* d_ws, size_t ws_size,
                              hipStream_t stream) {
    const int*   edge_index = (const int*)d_in[0];
    const float* edge_attr  = (const float*)d_in[1];
    const float* msg_init   = (const float*)d_in[2];
    const float* psi_init   = (const float*)d_in[3];
    const float* beta_p     = (const float*)d_in[4];

    const int E = in_sizes[1];      // 1,600,000
    const int M = E / 2;
    const int N = in_sizes[3] / Q;  // 50,000

    const int* src = edge_index;       // row 0
    const int* dst = edge_index + E;   // row 1

    float* out_msg = (float*)d_out;                  // doubles as mt ping buffer B
    float* out_psi = (float*)d_out + (size_t)E * Q;

    // workspace carve-up (256B aligned)
    char* ws = (char*)d_ws;
    size_t off = 0;
    auto alloc = [&](size_t bytes) -> void* {
        void* p = (void*)(ws + off);
        off = (off + bytes + 255) & ~(size_t)255;
        return p;
    };
    float* bufA      = (float*)alloc((size_t)E * Q * sizeof(float));       // 51.2 MB
    int4*  aux4      = (int4*)alloc((size_t)E * sizeof(int4));             // 25.6 MB
    int*   p_local   = (int*)alloc((size_t)E * sizeof(int));               // 6.4 MB
    int*   count     = (int*)alloc((size_t)N * CSTRIDE * sizeof(int));     // 3.2 MB
    int*   row_start = (int*)alloc((size_t)(N + 1) * sizeof(int));
    int*   blocksum  = (int*)alloc(64 * sizeof(int));
    float* hacc3     = (float*)alloc(3 * NSTRIPE * Q * sizeof(float));     // 6 KB
    (void)ws_size;

    const int gE   = (E + TB - 1) / TB;
    const int gM   = (M + TB - 1) / TB;
    const int gF   = (N + WPB - 1) / WPB;
    const int nblk = (N + SCB - 1) / SCB;   // 49
    const float invN = 1.0f / (float)N;

    // ---- setup ----
    hipMemsetAsync(count, 0, (size_t)N * CSTRIDE * sizeof(int), stream);
    hipMemsetAsync(hacc3, 0, 3 * NSTRIPE * Q * sizeof(float), stream);
    pass1_kernel<<<gE, TB, 0, stream>>>(dst, count, p_local, E);
    scanA_kernel<<<nblk, SCB, 0, stream>>>(count, row_start, blocksum,
                                           psi_init, hacc3, N);
    scanB_kernel<<<1, 64, 0, stream>>>(blocksum, row_start, nblk, N);
    scanC_kernel<<<nblk, SCB, 0, stream>>>(row_start, blocksum, N);
    aux_kernel<<<gM, TB, 0, stream>>>(src, dst, p_local, row_start, edge_attr,
                                      beta_p, msg_init, aux4, out_msg, M);

    // ---- 10 iterations; hacc rotation: read t%3, accumulate (t+1)%3, zero (t+2)%3 ----
    const float* cur = out_msg;   // holds mt_init
    float*       alt = bufA;
    for (int t = 0; t < NITER - 1; ++t) {
        bp_iter_kernel<false><<<gF, TBW, 0, stream>>>(
            cur, aux4, row_start, beta_p,
            hacc3 + (size_t)(t % 3) * NSTRIPE * Q,
            hacc3 + (size_t)((t + 1) % 3) * NSTRIPE * Q,
            hacc3 + (size_t)((t + 2) % 3) * NSTRIPE * Q,
            alt, out_psi, N, M, invN);
        float* tmp = (float*)cur; cur = alt; alt = tmp;
    }
    {
        int t = NITER - 1;
        bp_iter_kernel<true><<<gF, TBW, 0, stream>>>(
            cur, aux4, row_start, beta_p,
            hacc3 + (size_t)(t % 3) * NSTRIPE * Q,
            hacc3 + (size_t)((t + 1) % 3) * NSTRIPE * Q,
            hacc3 + (size_t)((t + 2) % 3) * NSTRIPE * Q,
            out_msg, out_psi, N, M, invN);
    }
}